// Round 4
// baseline (84.878 us; speedup 1.0000x reference)
//
#include <hip/hip_runtime.h>

// Single-dispatch consistent-loss kernel. One block (1024 threads, 1 CU):
//   per-column scatter-max of up into 51 value buckets (one side at a time,
//   LDS table [col][bucket] = 256x51 ints = 52 KB), then masked |diff| sums
//   vs left/right, block reduction, plain store to d_out (no memset needed).
//
// Bank-conflict design: lane <-> column, tab word index = c*51 + b;
// per-lane stride 51 words, gcd(51,32)=1 -> 32 distinct banks -> 2-way (free).
//
// Geometry hard-coded: H=W=256, row split at 128, bucket=round(up*50+110)-110
// in [0,50], mask up >= 0.0235, threshold 0.2, output /65536 exact.

__global__ __launch_bounds__(1024) void consist_loss_1blk(
    const float* __restrict__ up,
    const float* __restrict__ left,
    const float* __restrict__ right,
    float* __restrict__ out) {
#pragma clang fp contract(off)
    const int t = threadIdx.x;
    const int c  = t & 255;      // column of up (== output row of up2{l,r})
    const int rb = t >> 8;       // row-group 0..3 (32 rows each per side)

    __shared__ alignas(16) int tab[256 * 51];  // [col][bucket] float bits (nonneg)
    __shared__ float wsum[16];                 // per-wave partials

    float part = 0.0f;

    // side 0 = LEFT (rows 0..127, v=(128-r)/60), side 1 = RIGHT (rows 128..255, v=(r-128)/60)
    for (int side = 0; side < 2; ++side) {
        // ---- zero table: 13056 ints = 3264 int4 ----
        for (int i = t; i < 3264; i += 1024)
            ((int4*)tab)[i] = make_int4(0, 0, 0, 0);
        __syncthreads();

        // ---- scatter-max: 32 rows per thread, lane<->column (coalesced) ----
#pragma unroll 4
        for (int k = 0; k < 32; ++k) {
            const int rl = rb * 32 + k;              // local row 0..127
            const int r  = side ? 128 + rl : rl;     // global row
            const float u = up[r * 256 + c];
            // match XLA: plain division (contract off)
            const float v = side ? (float)(r - 128) / 60.0f
                                 : (float)(128 - r) / 60.0f;
            const int vb = __float_as_int(v);        // v>=0 -> int order == float order
            if (u >= 0.0235f && vb != 0) {           // vb==0 only at r==128 (no-op anyway)
                // match XLA: mul then add (no FMA), round-half-even
                float s = u * 50.0f;
                s = s + 110.0f;
                const int b = (int)rintf(s) - 110;   // 0..50
                atomicMax(&tab[c * 51 + b], vb);
            }
        }
        __syncthreads();

        // ---- compare phase: 13056 (col,bucket) entries vs ref row c, col 110+b ----
        const float* __restrict__ ref = side ? right : left;
        for (int i = t; i < 13056; i += 1024) {
            const int ti = tab[i];
            if (ti != 0) {
                const int cc = i / 51;           // col of up == row of ref
                const int b  = i - cc * 51;      // bucket -> ref col 110+b
                const float d = fabsf(__int_as_float(ti) - ref[cc * 256 + 110 + b]);
                if (d < 0.2f) part += d;
            }
        }
        __syncthreads();   // before re-zeroing tab for the next side
    }

    // ---- block reduction: wave shuffle, then 16 wave-partials ----
    part += __shfl_down(part, 32);
    part += __shfl_down(part, 16);
    part += __shfl_down(part, 8);
    part += __shfl_down(part, 4);
    part += __shfl_down(part, 2);
    part += __shfl_down(part, 1);
    if ((t & 63) == 0) wsum[t >> 6] = part;
    __syncthreads();
    if (t < 16) {
        float x = wsum[t];
        x += __shfl_down(x, 8);
        x += __shfl_down(x, 4);
        x += __shfl_down(x, 2);
        x += __shfl_down(x, 1);
        if (t == 0)
            out[0] = x * (1.0f / 65536.0f);   // mean_r + mean_l, exact pow2 scale
    }
}

extern "C" void kernel_launch(void* const* d_in, const int* in_sizes, int n_in,
                              void* d_out, int out_size, void* d_ws, size_t ws_size,
                              hipStream_t stream) {
    const float* up    = (const float*)d_in[0];
    const float* left  = (const float*)d_in[1];
    const float* right = (const float*)d_in[2];
    float* out = (float*)d_out;

    // Single dispatch; d_out is overwritten by a plain store (no memset needed).
    consist_loss_1blk<<<1, 1024, 0, stream>>>(up, left, right, out);
}

// Round 7
// 59.713 us; speedup vs baseline: 1.4214x; 1.4214x over previous
//
#include <hip/hip_runtime.h>

// Consistent-loss, two tiny dispatches, no memset / no atomics-to-out:
//   K1: 256 blocks (one per up-column j) x 256 threads (one per row i):
//       LDS scatter-max into 51 value buckets per side, masked |diff| sums
//       vs left/right row j, wave-0 reduce, partial -> d_ws[j].
//   K2: one wave sums the 256 partials and stores sum/65536 to d_out.
//
// Geometry hard-coded: H=W=256, row split at 128, bucket=round(up*50+110)
// in [110,160] (51 slots), mask up >= 0.0235, threshold 0.2.

__global__ __launch_bounds__(256) void consist_partial_kernel(
    const float* __restrict__ up,
    const float* __restrict__ left,
    const float* __restrict__ right,
    float* __restrict__ ws) {
#pragma clang fp contract(off)
    const int j = blockIdx.x;    // column of `up` == output row of up2{l,r}
    const int t = threadIdx.x;   // row index i

    __shared__ int u2r[64];      // slots 0..50 hold float bits (nonneg -> int order == float order)
    __shared__ int u2l[64];

    if (t < 64) { u2r[t] = 0; u2l[t] = 0; }
    __syncthreads();

    // ---- Phase A: scatter-max over rows i of column j ----
    const float u = up[t * 256 + j];
    if (u >= 0.0235f) {
        // match XLA: mul then add (no FMA), then round-half-even
        float s = u * 50.0f;
        s = s + 110.0f;
        const int b = (int)rintf(s) - 110;   // 0..50
        if (t > 128) {
            const float v = (float)(t - 128) / 60.0f;   // val_r > 0
            atomicMax(&u2r[b], __float_as_int(v));
        } else if (t < 128) {
            const float v = (float)(128 - t) / 60.0f;   // val_l > 0
            atomicMax(&u2l[b], __float_as_int(v));
        }
        // t == 128: val_l == 0 -> no-op against zero-init buffer
    }
    __syncthreads();

    // ---- Phase B: masked |diff| sums at row j, cols 110..160 ----
    float part = 0.0f;
    if (t < 51) {
        const int c = 110 + t;
        const float ur = __int_as_float(u2r[t]);
        if (ur != 0.0f) {
            const float d = fabsf(ur - right[j * 256 + c]);
            if (d < 0.2f) part += d;
        }
        const float ul = __int_as_float(u2l[t]);
        if (ul != 0.0f) {
            const float d = fabsf(ul - left[j * 256 + c]);
            if (d < 0.2f) part += d;
        }
    }

    // ---- wave-0 reduction (all nonzero parts live in lanes 0..50) ----
    if (t < 64) {
        part += __shfl_down(part, 32);
        part += __shfl_down(part, 16);
        part += __shfl_down(part, 8);
        part += __shfl_down(part, 4);
        part += __shfl_down(part, 2);
        part += __shfl_down(part, 1);
        if (t == 0) ws[j] = part;            // unscaled block partial
    }
}

__global__ __launch_bounds__(64) void consist_reduce_kernel(
    const float* __restrict__ ws,
    float* __restrict__ out) {
    const int t = threadIdx.x;
    const float4 v = ((const float4*)ws)[t];   // 64 lanes x 4 = 256 partials
    float s = (v.x + v.y) + (v.z + v.w);
    s += __shfl_down(s, 32);
    s += __shfl_down(s, 16);
    s += __shfl_down(s, 8);
    s += __shfl_down(s, 4);
    s += __shfl_down(s, 2);
    s += __shfl_down(s, 1);
    if (t == 0)
        out[0] = s * (1.0f / 65536.0f);   // mean_r + mean_l, exact pow2 scale
}

extern "C" void kernel_launch(void* const* d_in, const int* in_sizes, int n_in,
                              void* d_out, int out_size, void* d_ws, size_t ws_size,
                              hipStream_t stream) {
    const float* up    = (const float*)d_in[0];
    const float* left  = (const float*)d_in[1];
    const float* right = (const float*)d_in[2];
    float* ws  = (float*)d_ws;
    float* out = (float*)d_out;

    consist_partial_kernel<<<256, 256, 0, stream>>>(up, left, right, ws);
    consist_reduce_kernel<<<1, 64, 0, stream>>>(ws, out);
}